// Round 1
// baseline (577.929 us; speedup 1.0000x reference)
//
#include <hip/hip_runtime.h>

// ---------------------------------------------------------------------------
// SparseLoRAMoE: out = (gate ⊙ (x @ A_flat^T)) @ Bflat * 0.5
//   N=16384 tokens, D=4096, E=8 experts, R=16, C=E*R=128, O=4096, TOP_K=2
// Round 0: 5 kernels (prep, router, gemm1-ksplit, combine, gemm2)
// ---------------------------------------------------------------------------

#define NTOK   16384
#define DDIM   4096
#define NEXP   8
#define CDIM   128     // E*R
#define ODIM   4096

typedef float  f32x4  __attribute__((ext_vector_type(4)));
typedef __bf16 bf16x8 __attribute__((ext_vector_type(8)));
typedef unsigned short ushort8 __attribute__((ext_vector_type(8)));

__device__ __forceinline__ unsigned short f2bf(float f) {
    union { float f; unsigned u; } v; v.f = f;
    unsigned r = v.u + 0x7FFFu + ((v.u >> 16) & 1u);   // RNE
    return (unsigned short)(r >> 16);
}

// ---------------------------------------------------------------------------
// prep: A [128,4096] fp32 -> bf16 (same layout); Bm [8,4096,16] fp32 ->
//       Bt [o=4096][c=128] bf16 (o-major, c contiguous)
// grid 4096 x 256
// ---------------------------------------------------------------------------
__global__ void prep_kernel(const float* __restrict__ A,
                            const float* __restrict__ Bm,
                            unsigned short* __restrict__ A_bf,
                            unsigned short* __restrict__ Bt) {
    int i = blockIdx.x * 256 + threadIdx.x;
    if (i < CDIM * DDIM) {
        A_bf[i] = f2bf(A[i]);
    } else {
        int j = i - CDIM * DDIM;           // j = o*128 + c
        int o = j >> 7, c = j & 127;
        int e = c >> 4, r = c & 15;
        Bt[j] = f2bf(Bm[((size_t)e * ODIM + o) * 16 + r]);
    }
}

// ---------------------------------------------------------------------------
// router: fp32 logits, softmax-top2 gates (pre-scaled by 0.5).
// One wave handles 8 tokens; lanes tile D with float4 (coalesced 1KB/load).
// grid 512 x 256 (4 waves x 8 tokens = 32 tokens / block)
// ---------------------------------------------------------------------------
__global__ __launch_bounds__(256) void router_kernel(const float* __restrict__ x,
                                                     const float* __restrict__ rw,
                                                     const float* __restrict__ rbias,
                                                     float* __restrict__ gates) {
    int wv = threadIdx.x >> 6, lane = threadIdx.x & 63;
    int tok0 = blockIdx.x * 32 + wv * 8;
    const float* xb = x + (size_t)tok0 * DDIM;

    float acc[8][8];
    #pragma unroll
    for (int t = 0; t < 8; t++)
        #pragma unroll
        for (int e = 0; e < 8; e++) acc[t][e] = 0.f;

    for (int i = 0; i < 16; i++) {
        int d = i * 256 + lane * 4;
        float4 xv[8];
        #pragma unroll
        for (int t = 0; t < 8; t++)
            xv[t] = *(const float4*)(xb + (size_t)t * DDIM + d);
        #pragma unroll
        for (int e = 0; e < 8; e++) {
            float4 w4 = *(const float4*)(rw + (size_t)e * DDIM + d);
            #pragma unroll
            for (int t = 0; t < 8; t++)
                acc[t][e] += xv[t].x * w4.x + xv[t].y * w4.y +
                             xv[t].z * w4.z + xv[t].w * w4.w;
        }
    }

    // butterfly reduce across 64 lanes (all lanes end with the full sums)
    #pragma unroll
    for (int t = 0; t < 8; t++)
        #pragma unroll
        for (int e = 0; e < 8; e++) {
            float v = acc[t][e];
            #pragma unroll
            for (int m = 32; m >= 1; m >>= 1) v += __shfl_xor(v, m, 64);
            acc[t][e] = v;
        }

    if (lane == 0) {
        float rb0[8];
        #pragma unroll
        for (int e = 0; e < 8; e++) rb0[e] = rbias[e];
        #pragma unroll
        for (int t = 0; t < 8; t++) {
            float l[8];
            #pragma unroll
            for (int e = 0; e < 8; e++) l[e] = acc[t][e] + rb0[e];
            int a1 = 0; float m1 = l[0];
            #pragma unroll
            for (int e = 1; e < 8; e++) if (l[e] > m1) { m1 = l[e]; a1 = e; }
            int a2 = -1; float m2 = -3.0e38f;
            #pragma unroll
            for (int e = 0; e < 8; e++) if (e != a1 && l[e] > m2) { m2 = l[e]; a2 = e; }
            float g1 = 1.f / (1.f + expf(m2 - m1));
            float g2 = 1.f - g1;
            float go[8];
            #pragma unroll
            for (int e = 0; e < 8; e++)
                go[e] = (e == a1) ? g1 * 0.5f : ((e == a2) ? g2 * 0.5f : 0.f);
            float4* gp = (float4*)(gates + (size_t)(tok0 + t) * 8);
            gp[0] = make_float4(go[0], go[1], go[2], go[3]);
            gp[1] = make_float4(go[4], go[5], go[6], go[7]);
        }
    }
}

// ---------------------------------------------------------------------------
// gemm1: P[kh][n][c] = sum_{k in half kh} bf16(x[n][k]) * A_bf[c][k]  (fp32)
// BM=64, BK=32, Ksplit=2 -> grid 512 (2 blocks/CU), 256 threads (4 waves).
// Wave wv handles rows wv*16..+15, all 8 col-frags. Register prefetch depth 1.
// ---------------------------------------------------------------------------
__global__ __launch_bounds__(256, 2) void g1_kernel(const float* __restrict__ x,
                                                    const unsigned short* __restrict__ A_bf,
                                                    float* __restrict__ P) {
    __shared__ alignas(16) unsigned short xt[64 * 40];    // [row][32+8 pad]
    __shared__ alignas(16) unsigned short at[128 * 40];

    int tid = threadIdx.x;
    int wv = tid >> 6, lane = tid & 63;
    int rb = blockIdx.x >> 1, kh = blockIdx.x & 1;
    int row0 = rb * 64;
    size_t kbase = (size_t)kh * 2048;

    int sr = tid >> 2, sq = tid & 3;        // x staging: row sr, 8 floats at sq*8
    const float* xsrc = x + (size_t)(row0 + sr) * DDIM + kbase + sq * 8;
    int ac = tid >> 1, ah = tid & 1;        // A staging: row ac, 16 bf16 at ah*16
    const unsigned short* asrc = A_bf + (size_t)ac * DDIM + kbase + ah * 16;

    int xoff = sr * 40 + sq * 8;
    int aoff = ac * 40 + ah * 16;

    f32x4 acc[8];
    #pragma unroll
    for (int f = 0; f < 8; f++) acc[f] = (f32x4){0.f, 0.f, 0.f, 0.f};

    // prefetch tile 0
    float4 px0 = *(const float4*)(xsrc);
    float4 px1 = *(const float4*)(xsrc + 4);
    uint4  pa0 = *(const uint4*)(asrc);
    uint4  pa1 = *(const uint4*)(asrc + 8);

    int am = (wv * 16 + (lane & 15)) * 40 + (lane >> 4) * 8;
    int bq = (lane & 15) * 40 + (lane >> 4) * 8;

    for (int it = 0; it < 64; it++) {
        ushort8 xw;
        xw[0] = f2bf(px0.x); xw[1] = f2bf(px0.y); xw[2] = f2bf(px0.z); xw[3] = f2bf(px0.w);
        xw[4] = f2bf(px1.x); xw[5] = f2bf(px1.y); xw[6] = f2bf(px1.z); xw[7] = f2bf(px1.w);
        if (it) __syncthreads();           // previous tile's readers done
        *(ushort8*)(&xt[xoff]) = xw;
        *(uint4*)(&at[aoff])     = pa0;
        *(uint4*)(&at[aoff + 8]) = pa1;
        if (it + 1 < 64) {                 // issue next-tile loads, overlap MFMA
            xsrc += 32;  asrc += 32;
            px0 = *(const float4*)(xsrc);
            px1 = *(const float4*)(xsrc + 4);
            pa0 = *(const uint4*)(asrc);
            pa1 = *(const uint4*)(asrc + 8);
        }
        __syncthreads();
        bf16x8 a = *(bf16x8*)(&xt[am]);
        #pragma unroll
        for (int f = 0; f < 8; f++) {
            bf16x8 b = *(bf16x8*)(&at[f * 16 * 40 + bq]);
            acc[f] = __builtin_amdgcn_mfma_f32_16x16x32_bf16(a, b, acc[f], 0, 0, 0);
        }
    }

    float* Pk = P + (size_t)kh * NTOK * CDIM;
    int rbase = row0 + wv * 16 + (lane >> 4) * 4;
    int cl = lane & 15;
    #pragma unroll
    for (int f = 0; f < 8; f++)
        #pragma unroll
        for (int r = 0; r < 4; r++)
            Pk[(size_t)(rbase + r) * CDIM + f * 16 + cl] = acc[f][r];
}

// ---------------------------------------------------------------------------
// combine: Mg[n][c] = bf16( (P0+P1)[n][c] * gates[n][c>>4] )
// grid 2048 x 256, 4 elements/thread
// ---------------------------------------------------------------------------
__global__ void kc_kernel(const float* __restrict__ P,
                          const float* __restrict__ gates,
                          unsigned short* __restrict__ Mg) {
    int i = blockIdx.x * 256 + threadIdx.x;
    int base = i * 4;
    int n = base >> 7, c0 = base & 127;
    float g = gates[(size_t)n * 8 + (c0 >> 4)];
    float4 a = *(const float4*)(P + base);
    float4 b = *(const float4*)(P + (size_t)NTOK * CDIM + base);
    ushort4 o;
    o.x = f2bf((a.x + b.x) * g);
    o.y = f2bf((a.y + b.y) * g);
    o.z = f2bf((a.z + b.z) * g);
    o.w = f2bf((a.w + b.w) * g);
    *(ushort4*)(Mg + base) = o;
}

// ---------------------------------------------------------------------------
// gemm2: out[n][o] = sum_c Mg[n][c] * Bt[o][c]   (K=128, single shot)
// BM=64, BN=128 -> grid 8192 (256 row-blocks x 32 col-blocks), 256 threads.
// ---------------------------------------------------------------------------
__global__ __launch_bounds__(256, 2) void g2_kernel(const unsigned short* __restrict__ Mg,
                                                    const unsigned short* __restrict__ Bt,
                                                    float* __restrict__ out) {
    __shared__ alignas(16) unsigned short mt[64 * 136];    // [row][128+8]
    __shared__ alignas(16) unsigned short bt[128 * 136];

    int tid = threadIdx.x, wv = tid >> 6, lane = tid & 63;
    int cb = blockIdx.x & 31, rb = blockIdx.x >> 5;
    int row0 = rb * 64, col0 = cb * 128;

    {   // stage M tile: 64 x 128 bf16 = 16 KB, 64 B/thread
        int r = tid >> 2, q = tid & 3;
        const uint4* src = (const uint4*)(Mg + (size_t)(row0 + r) * CDIM + q * 32);
        uint4 v0 = src[0], v1 = src[1], v2 = src[2], v3 = src[3];
        uint4* dst = (uint4*)(&mt[r * 136 + q * 32]);
        dst[0] = v0; dst[1] = v1; dst[2] = v2; dst[3] = v3;
    }
    {   // stage B tile: 128 x 128 bf16 = 32 KB, 128 B/thread
        int o = tid >> 1, h = tid & 1;
        const uint4* src = (const uint4*)(Bt + (size_t)(col0 + o) * CDIM + h * 64);
        uint4 v0 = src[0], v1 = src[1], v2 = src[2], v3 = src[3];
        uint4 v4 = src[4], v5 = src[5], v6 = src[6], v7 = src[7];
        uint4* dst = (uint4*)(&bt[o * 136 + h * 64]);
        dst[0] = v0; dst[1] = v1; dst[2] = v2; dst[3] = v3;
        dst[4] = v4; dst[5] = v5; dst[6] = v6; dst[7] = v7;
    }
    __syncthreads();

    f32x4 acc[8];
    #pragma unroll
    for (int f = 0; f < 8; f++) acc[f] = (f32x4){0.f, 0.f, 0.f, 0.f};

    int mrow = (wv * 16 + (lane & 15)) * 136;
    int kq = (lane >> 4) * 8;
    #pragma unroll
    for (int kk = 0; kk < 4; kk++) {
        bf16x8 a = *(bf16x8*)(&mt[mrow + kk * 32 + kq]);
        #pragma unroll
        for (int f = 0; f < 8; f++) {
            bf16x8 b = *(bf16x8*)(&bt[(f * 16 + (lane & 15)) * 136 + kk * 32 + kq]);
            acc[f] = __builtin_amdgcn_mfma_f32_16x16x32_bf16(a, b, acc[f], 0, 0, 0);
        }
    }

    int rbase = row0 + wv * 16 + (lane >> 4) * 4;
    int cl = lane & 15;
    #pragma unroll
    for (int f = 0; f < 8; f++)
        #pragma unroll
        for (int r = 0; r < 4; r++)
            out[(size_t)(rbase + r) * ODIM + col0 + f * 16 + cl] = acc[f][r];
}

// ---------------------------------------------------------------------------
extern "C" void kernel_launch(void* const* d_in, const int* in_sizes, int n_in,
                              void* d_out, int out_size, void* d_ws, size_t ws_size,
                              hipStream_t stream) {
    const float* x    = (const float*)d_in[0];
    const float* rw   = (const float*)d_in[1];
    const float* rbia = (const float*)d_in[2];
    const float* A    = (const float*)d_in[3];
    const float* Bm   = (const float*)d_in[4];
    float* out = (float*)d_out;

    char* ws = (char*)d_ws;
    unsigned short* A_bf = (unsigned short*)(ws);                     // 1 MB
    unsigned short* Bt   = (unsigned short*)(ws + (1u << 20));        // 1 MB
    float* gates         = (float*)(ws + (2u << 20));                 // 512 KB
    float* P             = (float*)(ws + (2u << 20) + (1u << 19));    // 16 MB
    unsigned short* Mg   = (unsigned short*)(ws + (2u << 20) + (1u << 19) + (16u << 20)); // 4 MB

    prep_kernel  <<<4096, 256, 0, stream>>>(A, Bm, A_bf, Bt);
    router_kernel<<< 512, 256, 0, stream>>>(x, rw, rbia, gates);
    g1_kernel    <<< 512, 256, 0, stream>>>(x, A_bf, P);
    kc_kernel    <<<2048, 256, 0, stream>>>(P, gates, Mg);
    g2_kernel    <<<8192, 256, 0, stream>>>(Mg, Bt, out);
}